// Round 1
// baseline (9443.221 us; speedup 1.0000x reference)
//
#include <hip/hip_runtime.h>
#include <hip/hip_bf16.h>
#include <math.h>

// Problem constants
#define V_  32000
#define D_  512
#define DFF_ 2048
#define L_  4
#define H_  8
#define N_  64
#define K_  8
#define NB_ 32
#define R_  64
#define B_  2
#define S_  512
#define T_  1024   // B*S
#define DH_ 64

// ---------------------------------------------------------------- GEMM (fp32)
// C[M,N] = A[M,K] @ B[K,N] (+bias). BT=true: B is [N,K] row-major.
// 128x128 tile, BK=8, 256 threads, 8x8 microtile.
template<bool BT>
__global__ __launch_bounds__(256) void gemm_f32(
    const float* __restrict__ A, int lda, long sA,
    const float* __restrict__ B, int ldb, long sB,
    const float* __restrict__ bias,
    float* __restrict__ C, int ldc, long sC,
    int M, int N, int K)
{
    __shared__ float As[8][132];
    __shared__ float Bs[8][132];
    int z = blockIdx.z;
    A += (long)z * sA; B += (long)z * sB; C += (long)z * sC;
    int bm = blockIdx.y * 128, bn = blockIdx.x * 128;
    int tid = threadIdx.x;
    int tm = tid >> 4, tn = tid & 15;
    float acc[8][8] = {};
    int mBase = bm + tm * 8, nBase = bn + tn * 8;

    for (int k0 = 0; k0 < K; k0 += 8) {
        #pragma unroll
        for (int i = 0; i < 4; i++) {
            int idx = tid + i * 256;
            int m = idx >> 3, kk = idx & 7;
            int gm = bm + m;
            As[kk][m] = (gm < M) ? A[(long)gm * lda + k0 + kk] : 0.f;
        }
        if (!BT) {
            #pragma unroll
            for (int i = 0; i < 4; i++) {
                int idx = tid + i * 256;
                int kk = idx >> 7, n = idx & 127;
                int gn = bn + n;
                Bs[kk][n] = (gn < N) ? B[(long)(k0 + kk) * ldb + gn] : 0.f;
            }
        } else {
            #pragma unroll
            for (int i = 0; i < 4; i++) {
                int idx = tid + i * 256;
                int n = idx >> 3, kk = idx & 7;
                int gn = bn + n;
                Bs[kk][n] = (gn < N) ? B[(long)gn * ldb + k0 + kk] : 0.f;
            }
        }
        __syncthreads();
        #pragma unroll
        for (int kk = 0; kk < 8; kk++) {
            float a[8], b[8];
            #pragma unroll
            for (int i = 0; i < 8; i++) a[i] = As[kk][tm * 8 + i];
            #pragma unroll
            for (int j = 0; j < 8; j++) b[j] = Bs[kk][tn * 8 + j];
            #pragma unroll
            for (int i = 0; i < 8; i++)
                #pragma unroll
                for (int j = 0; j < 8; j++) acc[i][j] += a[i] * b[j];
        }
        __syncthreads();
    }
    #pragma unroll
    for (int i = 0; i < 8; i++) {
        int m = mBase + i; if (m >= M) continue;
        #pragma unroll
        for (int j = 0; j < 8; j++) {
            int n = nBase + j; if (n >= N) continue;
            float v = acc[i][j];
            if (bias) v += bias[n];
            C[(long)m * ldc + n] = v;
        }
    }
}

// ---------------------------------------------------------------- helpers
__global__ void tbasis_kernel(const float* __restrict__ A, float* __restrict__ At) {
    // A[n][d][r] -> At[n][r][d]
    long i = (long)blockIdx.x * blockDim.x + threadIdx.x;
    if (i >= (long)NB_ * D_ * R_) return;
    int r = i % R_; int d = (i / R_) % D_; int n = i / ((long)R_ * D_);
    At[((long)n * R_ + r) * D_ + d] = A[i];
}

__global__ void embed_kernel(const int* __restrict__ ids, const float* __restrict__ temb,
                             const float* __restrict__ pemb, float* __restrict__ x) {
    int t = blockIdx.x;
    int s = t % S_;
    int id = ids[t];
    for (int d = threadIdx.x; d < D_; d += blockDim.x)
        x[(long)t * D_ + d] = temb[(long)id * D_ + d] + pemb[(long)s * D_ + d];
}

__global__ __launch_bounds__(256) void ln_kernel(const float* __restrict__ in,
                                                 const float* __restrict__ g,
                                                 const float* __restrict__ b,
                                                 float* __restrict__ out) {
    int t = blockIdx.x;
    const float* row = in + (long)t * D_;
    int tid = threadIdx.x;
    float v0 = row[tid], v1 = row[tid + 256];
    __shared__ float red[256];
    red[tid] = v0 + v1; __syncthreads();
    for (int off = 128; off; off >>= 1) { if (tid < off) red[tid] += red[tid + off]; __syncthreads(); }
    float mean = red[0] * (1.0f / D_); __syncthreads();
    float d0 = v0 - mean, d1 = v1 - mean;
    red[tid] = d0 * d0 + d1 * d1; __syncthreads();
    for (int off = 128; off; off >>= 1) { if (tid < off) red[tid] += red[tid + off]; __syncthreads(); }
    float rstd = rsqrtf(red[0] * (1.0f / D_) + 1e-5f);
    out[(long)t * D_ + tid]       = d0 * rstd * g[tid]       + b[tid];
    out[(long)t * D_ + tid + 256] = d1 * rstd * g[tid + 256] + b[tid + 256];
}

__global__ __launch_bounds__(256) void attn_kernel(const float* __restrict__ q,
                                                   const float* __restrict__ k,
                                                   const float* __restrict__ v,
                                                   float* __restrict__ ctx) {
    int qi = blockIdx.x, h = blockIdx.y, b = blockIdx.z;
    __shared__ float s[S_];
    __shared__ float qs[DH_];
    __shared__ float red[256];
    __shared__ float part[4][DH_];
    long base = ((long)b * S_ * H_ + h) * DH_;  // + j*H_*DH_
    int tid = threadIdx.x;
    if (tid < DH_) qs[tid] = q[base + (long)qi * (H_ * DH_) + tid];
    __syncthreads();
    int nk = qi + 1;
    float lmax = -INFINITY;
    for (int j = tid; j < nk; j += 256) {
        const float* kr = k + base + (long)j * (H_ * DH_);
        float d = 0.f;
        #pragma unroll
        for (int u = 0; u < DH_; u++) d += qs[u] * kr[u];
        d *= 0.125f;
        s[j] = d; lmax = fmaxf(lmax, d);
    }
    red[tid] = lmax; __syncthreads();
    for (int off = 128; off; off >>= 1) { if (tid < off) red[tid] = fmaxf(red[tid], red[tid + off]); __syncthreads(); }
    float mx = red[0]; __syncthreads();
    float lsum = 0.f;
    for (int j = tid; j < nk; j += 256) { float e = expf(s[j] - mx); s[j] = e; lsum += e; }
    red[tid] = lsum; __syncthreads();
    for (int off = 128; off; off >>= 1) { if (tid < off) red[tid] += red[tid + off]; __syncthreads(); }
    float inv = 1.0f / red[0];
    int d = tid & 63, grp = tid >> 6;
    float acc = 0.f;
    for (int j = grp; j < nk; j += 4) acc += s[j] * v[base + (long)j * (H_ * DH_) + d];
    part[grp][d] = acc; __syncthreads();
    if (tid < DH_)
        ctx[base + (long)qi * (H_ * DH_) + tid] =
            (part[0][tid] + part[1][tid] + part[2][tid] + part[3][tid]) * inv;
}

__global__ void cat_kernel(const float* __restrict__ n1, const float* __restrict__ ctx,
                           float* __restrict__ cat) {
    long i = (long)blockIdx.x * blockDim.x + threadIdx.x;
    if (i >= (long)T_ * D_) return;
    int t = i >> 9, d = i & 511;
    cat[(long)t * 1024 + d] = n1[i];
    cat[(long)t * 1024 + 512 + d] = ctx[i];
}

__global__ void ne_kernel(const float* __restrict__ rec, const float* __restrict__ bemb,
                          float* __restrict__ ne, float* __restrict__ sel) {
    int n = blockIdx.x;
    __shared__ float w[NB_];
    if (threadIdx.x == 0) {
        float mx = -1e30f;
        for (int i = 0; i < NB_; i++) mx = fmaxf(mx, rec[n * NB_ + i]);
        float sm = 0.f;
        for (int i = 0; i < NB_; i++) { float e = expf(rec[n * NB_ + i] - mx); w[i] = e; sm += e; }
        float inv = 1.f / sm;
        for (int i = 0; i < NB_; i++) w[i] *= inv;
    }
    __syncthreads();
    if (threadIdx.x < NB_) sel[n * NB_ + threadIdx.x] = w[threadIdx.x];
    for (int d = threadIdx.x; d < D_; d += blockDim.x) {
        float acc = 0.f;
        #pragma unroll
        for (int nb = 0; nb < NB_; nb++) acc += w[nb] * bemb[nb * D_ + d];
        ne[(long)n * D_ + d] = acc;
    }
}

__global__ __launch_bounds__(64) void route_kernel(const float* __restrict__ scores,
                                                   const float* __restrict__ sel,
                                                   float* __restrict__ tr) {
    int t = blockIdx.x, lane = threadIdx.x;
    float myval = scores[(long)t * N_ + lane];
    float topv[K_]; int topi[K_];
    #pragma unroll
    for (int kk = 0; kk < K_; kk++) {
        float v = myval; int idx = lane;
        #pragma unroll
        for (int off = 32; off; off >>= 1) {
            float ov = __shfl_down(v, off);
            int oi = __shfl_down(idx, off);
            if (ov > v || (ov == v && oi < idx)) { v = ov; idx = oi; }
        }
        v = __shfl(v, 0); idx = __shfl(idx, 0);
        topv[kk] = v; topi[kk] = idx;
        if (lane == idx) myval = -INFINITY;
    }
    float mx = topv[0];
    float w[K_], sum = 0.f;
    #pragma unroll
    for (int kk = 0; kk < K_; kk++) { w[kk] = expf(topv[kk] - mx); sum += w[kk]; }
    float inv = 1.f / sum;
    if (lane < NB_) {
        float acc = 0.f;
        #pragma unroll
        for (int kk = 0; kk < K_; kk++) acc += w[kk] * inv * sel[topi[kk] * NB_ + lane];
        tr[(long)t * NB_ + lane] = acc;
    }
}

__global__ __launch_bounds__(64) void h_kernel(const float* __restrict__ tr,
                                               const float* __restrict__ proj,
                                               float* __restrict__ hb) {
    int t = blockIdx.x, r = threadIdx.x;
    const float* p = proj + (long)t * (NB_ * R_);
    const float* trr = tr + (long)t * NB_;
    float acc = 0.f;
    #pragma unroll
    for (int n = 0; n < NB_; n++) acc += trr[n] * p[n * R_ + r];
    hb[(long)t * R_ + r] = acc;
}

__global__ void g_kernel(const float* __restrict__ tr, const float* __restrict__ hb,
                         float* __restrict__ g) {
    long i = (long)blockIdx.x * blockDim.x + threadIdx.x;
    if (i >= (long)T_ * NB_ * R_) return;
    int t = i >> 11; int nr = i & 2047; int n = nr >> 6, r = nr & 63;
    g[i] = tr[t * NB_ + n] * hb[t * R_ + r];
}

__global__ void xf_kernel(float* __restrict__ n2xf, const float* __restrict__ delta,
                          const float* __restrict__ alpha, int l, long n) {
    long i = (long)blockIdx.x * blockDim.x + threadIdx.x;
    if (i < n) n2xf[i] = n2xf[i] + alpha[l] * delta[i];
}

__global__ void gelu_kernel(float* __restrict__ p, long n) {
    long i = (long)blockIdx.x * blockDim.x + threadIdx.x;
    if (i < n) { float x = p[i]; p[i] = 0.5f * x * (1.0f + erff(x * 0.70710678118654752f)); }
}

__global__ void add_kernel(float* __restrict__ x, const float* __restrict__ d, long n) {
    long i = (long)blockIdx.x * blockDim.x + threadIdx.x;
    if (i < n) x[i] += d[i];
}

// ---------------------------------------------------------------- launch
extern "C" void kernel_launch(void* const* d_in, const int* in_sizes, int n_in,
                              void* d_out, int out_size, void* d_ws, size_t ws_size,
                              hipStream_t stream) {
    const int*   ids    = (const int*)d_in[0];
    const float* temb   = (const float*)d_in[1];
    const float* pemb   = (const float*)d_in[2];
    const float* basisA = (const float*)d_in[3];
    const float* bemb   = (const float*)d_in[4];
    const float* recipe = (const float*)d_in[5];
    const float* Wq = (const float*)d_in[6],  *bq = (const float*)d_in[7];
    const float* Wk = (const float*)d_in[8],  *bk = (const float*)d_in[9];
    const float* Wv = (const float*)d_in[10], *bv = (const float*)d_in[11];
    const float* Ws = (const float*)d_in[12], *bs = (const float*)d_in[13];
    const float* Wup = (const float*)d_in[14], *bup = (const float*)d_in[15];
    const float* Wdn = (const float*)d_in[16], *bdn = (const float*)d_in[17];
    const float* ln1g = (const float*)d_in[18], *ln1b = (const float*)d_in[19];
    const float* ln2g = (const float*)d_in[20], *ln2b = (const float*)d_in[21];
    const float* alpha = (const float*)d_in[22];
    const float* lnfg = (const float*)d_in[23], *lnfb = (const float*)d_in[24];
    float* out = (float*)d_out;
    float* W = (float*)d_ws;

    // ws arena (float offsets)
    float* x    = W + 0;          // 524288
    float* buf1 = W + 524288;     // n1 / n2(xf) / final-LN   524288
    float* qb   = W + 1048576;    // q then query             524288
    float* kb   = W + 1572864;    // 524288
    float* vb   = W + 2097152;    // 524288
    float* ctxb = W + 2621440;    // 524288
    float* scb  = W + 3145728;    // scores 65536
    float* trb  = W + 3211264;    // 32768
    float* hb   = W + 3244032;    // 65536
    float* ne   = W + 3309568;    // 32768
    float* sel  = W + 3342336;    // 2048
    float* At   = W + 3344384;    // 1048576
    float* P    = W + 4392960;    // proj / ffh  2097152
    float* G    = W + 6490112;    // cat / g     2097152
    float* DB   = W + 8587264;    // delta / ffdown 524288

    dim3 blk(256);
    // one-time (per call) transpose of basis_A
    tbasis_kernel<<<(NB_ * D_ * R_ + 255) / 256, blk, 0, stream>>>(basisA, At);
    embed_kernel<<<T_, blk, 0, stream>>>(ids, temb, pemb, x);

    for (int l = 0; l < L_; l++) {
        ne_kernel<<<N_, blk, 0, stream>>>(recipe + (long)l * N_ * NB_, bemb, ne, sel);
        ln_kernel<<<T_, blk, 0, stream>>>(x, ln1g + l * D_, ln1b + l * D_, buf1);
        // QKV
        dim3 gqkv((D_ + 127) / 128, (T_ + 127) / 128, 1);
        gemm_f32<false><<<gqkv, blk, 0, stream>>>(buf1, D_, 0, Wq + (long)l * D_ * D_, D_, 0,
                                                  bq + l * D_, qb, D_, 0, T_, D_, D_);
        gemm_f32<false><<<gqkv, blk, 0, stream>>>(buf1, D_, 0, Wk + (long)l * D_ * D_, D_, 0,
                                                  bk + l * D_, kb, D_, 0, T_, D_, D_);
        gemm_f32<false><<<gqkv, blk, 0, stream>>>(buf1, D_, 0, Wv + (long)l * D_ * D_, D_, 0,
                                                  bv + l * D_, vb, D_, 0, T_, D_, D_);
        attn_kernel<<<dim3(S_, H_, B_), blk, 0, stream>>>(qb, kb, vb, ctxb);
        cat_kernel<<<(T_ * D_ + 255) / 256, blk, 0, stream>>>(buf1, ctxb, G);
        // query = cat @ Ws + bs  (K=1024)
        gemm_f32<false><<<gqkv, blk, 0, stream>>>(G, 2 * D_, 0, Ws + (long)l * 2 * D_ * D_, D_, 0,
                                                  bs + l * D_, qb, D_, 0, T_, D_, 2 * D_);
        // scores = query @ ne^T
        dim3 gsc(1, (T_ + 127) / 128, 1);
        gemm_f32<true><<<gsc, blk, 0, stream>>>(qb, D_, 0, ne, D_, 0, nullptr,
                                                scb, N_, 0, T_, N_, D_);
        route_kernel<<<T_, dim3(64), 0, stream>>>(scb, sel, trb);
        // n2
        ln_kernel<<<T_, blk, 0, stream>>>(x, ln2g + l * D_, ln2b + l * D_, buf1);
        // proj: batched over n: [T,512] @ A_n[512,64] -> P[t, n*64+r]
        dim3 gpr(1, (T_ + 127) / 128, NB_);
        gemm_f32<false><<<gpr, blk, 0, stream>>>(buf1, D_, 0, basisA, R_, (long)D_ * R_, nullptr,
                                                 P, NB_ * R_, R_, T_, R_, D_);
        h_kernel<<<T_, dim3(64), 0, stream>>>(trb, P, hb);
        g_kernel<<<(T_ * NB_ * R_ + 255) / 256, blk, 0, stream>>>(trb, hb, G);
        // delta = G[T,2048] @ At[2048,512]
        dim3 gdl((D_ + 127) / 128, (T_ + 127) / 128, 1);
        gemm_f32<false><<<gdl, blk, 0, stream>>>(G, NB_ * R_, 0, At, D_, 0, nullptr,
                                                 DB, D_, 0, T_, D_, NB_ * R_);
        xf_kernel<<<(T_ * D_ + 255) / 256, blk, 0, stream>>>(buf1, DB, alpha, l, (long)T_ * D_);
        // FFN
        dim3 gup((DFF_ + 127) / 128, (T_ + 127) / 128, 1);
        gemm_f32<false><<<gup, blk, 0, stream>>>(buf1, D_, 0, Wup + (long)l * D_ * DFF_, DFF_, 0,
                                                 bup + l * DFF_, P, DFF_, 0, T_, DFF_, D_);
        gelu_kernel<<<(T_ * DFF_ + 255) / 256, blk, 0, stream>>>(P, (long)T_ * DFF_);
        gemm_f32<false><<<gdl, blk, 0, stream>>>(P, DFF_, 0, Wdn + (long)l * DFF_ * D_, D_, 0,
                                                 bdn + l * D_, DB, D_, 0, T_, D_, DFF_);
        add_kernel<<<(T_ * D_ + 255) / 256, blk, 0, stream>>>(x, DB, (long)T_ * D_);
    }
    // final LN + tied head
    ln_kernel<<<T_, blk, 0, stream>>>(x, lnfg, lnfb, buf1);
    dim3 ghd((V_ + 127) / 128, (T_ + 127) / 128, 1);
    gemm_f32<true><<<ghd, blk, 0, stream>>>(buf1, D_, 0, temb, D_, 0, nullptr,
                                            out, V_, 0, T_, V_, D_);
}

// Round 2
// 1330.210 us; speedup vs baseline: 7.0990x; 7.0990x over previous
//
#include <hip/hip_runtime.h>
#include <hip/hip_bf16.h>
#include <math.h>

// Problem constants
#define V_  32000
#define D_  512
#define DFF_ 2048
#define L_  4
#define H_  8
#define N_  64
#define K_  8
#define NB_ 32
#define R_  64
#define B_  2
#define S_  512
#define T_  1024   // B*S
#define DH_ 64

typedef short bhalf8 __attribute__((ext_vector_type(8)));
typedef float floatx4 __attribute__((ext_vector_type(4)));

#define GLOAD16(gp, lp) __builtin_amdgcn_global_load_lds( \
    (const __attribute__((address_space(1))) void*)(gp), \
    (__attribute__((address_space(3))) void*)(lp), 16, 0, 0)

__device__ __forceinline__ float gelu_f(float v) {
    return 0.5f * v * (1.0f + erff(v * 0.70710678118654752f));
}

// ------------------------------------------------------------- MFMA GEMM
// C[M,N] = A[M,K] @ Bt[N,K]^T (+bias). A,Bt bf16 row-major. 256 threads,
// 4 waves in WR x WC grid. BK=64, LDS XOR-swizzled (16B unit u ^= row&7).
// STORE: 0=f32, 1=bf16. ACT: 0=none, 1=gelu.
template<int BM, int BN, int WR, int WC, int STORE, int ACT>
__global__ __launch_bounds__(256) void gemm_mfma(
    const __hip_bfloat16* __restrict__ A, int lda, long sA,
    const __hip_bfloat16* __restrict__ Bt, int ldb, long sB,
    const float* __restrict__ bias,
    void* __restrict__ Cv, int ldc, long sC,
    int K)
{
    constexpr int FM = BM / WR / 16;
    constexpr int FN = BN / WC / 16;
    constexpr int ACH = BM * 8;   // 16B chunks in A tile (BM rows x 8 units)
    constexpr int BCH = BN * 8;
    __shared__ __align__(16) short As[BM * 64];
    __shared__ __align__(16) short Bs[BN * 64];
    const int tid = threadIdx.x;
    const int z = blockIdx.z;
    A  += (long)z * sA;
    Bt += (long)z * sB;
    const int bm = blockIdx.y * BM, bn = blockIdx.x * BN;
    const int w = tid >> 6, lane = tid & 63;
    const int wr = w / WC, wc = w % WC;
    const int moff = wr * (BM / WR), noff = wc * (BN / WC);
    floatx4 acc[FM][FN] = {};

    for (int k0 = 0; k0 < K; k0 += 64) {
        #pragma unroll
        for (int i = 0; i < ACH / 256; i++) {
            int c = tid + i * 256;
            int m = c >> 3, u = (c & 7) ^ (m & 7);     // pre-swizzled source
            const __hip_bfloat16* src = A + (long)(bm + m) * lda + k0 + u * 8;
            char* dst = (char*)As + (w * 64 + i * 256) * 16;  // wave-uniform base
            GLOAD16(src, dst);
        }
        #pragma unroll
        for (int i = 0; i < BCH / 256; i++) {
            int c = tid + i * 256;
            int m = c >> 3, u = (c & 7) ^ (m & 7);
            const __hip_bfloat16* src = Bt + (long)(bn + m) * ldb + k0 + u * 8;
            char* dst = (char*)Bs + (w * 64 + i * 256) * 16;
            GLOAD16(src, dst);
        }
        __syncthreads();
        #pragma unroll
        for (int kk = 0; kk < 2; kk++) {
            bhalf8 af[FM], bf[FN];
            #pragma unroll
            for (int fm = 0; fm < FM; fm++) {
                int row = moff + fm * 16 + (lane & 15);
                int u = (kk * 4 + (lane >> 4)) ^ (row & 7);
                af[fm] = *(const bhalf8*)((const char*)As + row * 128 + u * 16);
            }
            #pragma unroll
            for (int fn = 0; fn < FN; fn++) {
                int row = noff + fn * 16 + (lane & 15);
                int u = (kk * 4 + (lane >> 4)) ^ (row & 7);
                bf[fn] = *(const bhalf8*)((const char*)Bs + row * 128 + u * 16);
            }
            #pragma unroll
            for (int fm = 0; fm < FM; fm++)
                #pragma unroll
                for (int fn = 0; fn < FN; fn++)
                    acc[fm][fn] = __builtin_amdgcn_mfma_f32_16x16x32_bf16(
                        af[fm], bf[fn], acc[fm][fn], 0, 0, 0);
        }
        __syncthreads();
    }

    float* Cf = (float*)Cv;
    __hip_bfloat16* Cb = (__hip_bfloat16*)Cv;
    const long zoff = (long)z * sC;
    const int lr = lane >> 4, lc = lane & 15;
    #pragma unroll
    for (int fm = 0; fm < FM; fm++) {
        #pragma unroll
        for (int fn = 0; fn < FN; fn++) {
            int cN = bn + noff + fn * 16 + lc;
            float bv = bias ? bias[cN] : 0.f;
            #pragma unroll
            for (int i = 0; i < 4; i++) {
                int rM = bm + moff + fm * 16 + lr * 4 + i;
                float v = acc[fm][fn][i] + bv;
                if (ACT == 1) v = gelu_f(v);
                long idx = zoff + (long)rM * ldc + cN;
                if (STORE == 0) Cf[idx] = v;
                else            Cb[idx] = __float2bfloat16(v);
            }
        }
    }
}

// ------------------------------------------------------------- conversions
// out[n][k] = bf16(in[k][n]); 32x32 tiles.
__global__ __launch_bounds__(256) void tcvt(const float* __restrict__ in, int ldn, long sIn,
                                            __hip_bfloat16* __restrict__ out, int ldk, long sOut) {
    __shared__ float t[32][33];
    in  += (long)blockIdx.z * sIn;
    out += (long)blockIdx.z * sOut;
    int k0 = blockIdx.y * 32, n0 = blockIdx.x * 32;
    int tx = threadIdx.x & 31, ty = threadIdx.x >> 5;
    #pragma unroll
    for (int r = 0; r < 4; r++) t[ty * 4 + r][tx] = in[(long)(k0 + ty * 4 + r) * ldn + n0 + tx];
    __syncthreads();
    #pragma unroll
    for (int r = 0; r < 4; r++)
        out[(long)(n0 + ty * 4 + r) * ldk + k0 + tx] = __float2bfloat16(t[tx][ty * 4 + r]);
}

__global__ void cvt_temb(const float* __restrict__ in, __hip_bfloat16* __restrict__ out) {
    long i = ((long)blockIdx.x * 256 + threadIdx.x) * 4;
    float4 v = *(const float4*)(in + i);
    out[i]     = __float2bfloat16(v.x);
    out[i + 1] = __float2bfloat16(v.y);
    out[i + 2] = __float2bfloat16(v.z);
    out[i + 3] = __float2bfloat16(v.w);
}

__global__ void basis_prep(const float* __restrict__ A,
                           __hip_bfloat16* __restrict__ projT,
                           __hip_bfloat16* __restrict__ deltaT) {
    long i = (long)blockIdx.x * 256 + threadIdx.x;
    if (i >= (long)NB_ * D_ * R_) return;
    int r = i & 63; int d = (i >> 6) & 511; int n = i >> 15;
    __hip_bfloat16 v = __float2bfloat16(A[i]);
    projT[((long)n * R_ + r) * D_ + d] = v;
    deltaT[(long)d * (NB_ * R_) + n * R_ + r] = v;
}

// ------------------------------------------------------------- helpers
__global__ void embed_kernel(const int* __restrict__ ids, const float* __restrict__ temb,
                             const float* __restrict__ pemb, float* __restrict__ x) {
    int t = blockIdx.x;
    int s = t % S_;
    int id = ids[t];
    for (int d = threadIdx.x; d < D_; d += blockDim.x)
        x[(long)t * D_ + d] = temb[(long)id * D_ + d] + pemb[(long)s * D_ + d];
}

__global__ __launch_bounds__(256) void ln_kernel(const float* __restrict__ in,
                                                 const float* __restrict__ g,
                                                 const float* __restrict__ b,
                                                 float* __restrict__ outf,
                                                 __hip_bfloat16* __restrict__ outb) {
    int t = blockIdx.x;
    const float* row = in + (long)t * D_;
    int tid = threadIdx.x;
    float v0 = row[tid], v1 = row[tid + 256];
    __shared__ float red[256];
    red[tid] = v0 + v1; __syncthreads();
    for (int off = 128; off; off >>= 1) { if (tid < off) red[tid] += red[tid + off]; __syncthreads(); }
    float mean = red[0] * (1.0f / D_); __syncthreads();
    float d0 = v0 - mean, d1 = v1 - mean;
    red[tid] = d0 * d0 + d1 * d1; __syncthreads();
    for (int off = 128; off; off >>= 1) { if (tid < off) red[tid] += red[tid + off]; __syncthreads(); }
    float rstd = rsqrtf(red[0] * (1.0f / D_) + 1e-5f);
    float o0 = d0 * rstd * g[tid]       + b[tid];
    float o1 = d1 * rstd * g[tid + 256] + b[tid + 256];
    outf[(long)t * D_ + tid]       = o0;
    outf[(long)t * D_ + tid + 256] = o1;
    outb[(long)t * D_ + tid]       = __float2bfloat16(o0);
    outb[(long)t * D_ + tid + 256] = __float2bfloat16(o1);
}

__global__ __launch_bounds__(256) void attn_kernel(const float* __restrict__ q,
                                                   const float* __restrict__ k,
                                                   const float* __restrict__ v,
                                                   float* __restrict__ ctx) {
    int qi = blockIdx.x, h = blockIdx.y, b = blockIdx.z;
    __shared__ float s[S_];
    __shared__ float qs[DH_];
    __shared__ float red[256];
    __shared__ float part[4][DH_];
    long base = ((long)b * S_ * H_ + h) * DH_;
    int tid = threadIdx.x;
    if (tid < DH_) qs[tid] = q[base + (long)qi * (H_ * DH_) + tid];
    __syncthreads();
    int nk = qi + 1;
    float lmax = -INFINITY;
    for (int j = tid; j < nk; j += 256) {
        const float* kr = k + base + (long)j * (H_ * DH_);
        float d = 0.f;
        #pragma unroll
        for (int u = 0; u < DH_; u++) d += qs[u] * kr[u];
        d *= 0.125f;
        s[j] = d; lmax = fmaxf(lmax, d);
    }
    red[tid] = lmax; __syncthreads();
    for (int off = 128; off; off >>= 1) { if (tid < off) red[tid] = fmaxf(red[tid], red[tid + off]); __syncthreads(); }
    float mx = red[0]; __syncthreads();
    float lsum = 0.f;
    for (int j = tid; j < nk; j += 256) { float e = expf(s[j] - mx); s[j] = e; lsum += e; }
    red[tid] = lsum; __syncthreads();
    for (int off = 128; off; off >>= 1) { if (tid < off) red[tid] += red[tid + off]; __syncthreads(); }
    float inv = 1.0f / red[0];
    int d = tid & 63, grp = tid >> 6;
    float acc = 0.f;
    for (int j = grp; j < nk; j += 4) acc += s[j] * v[base + (long)j * (H_ * DH_) + d];
    part[grp][d] = acc; __syncthreads();
    if (tid < DH_)
        ctx[base + (long)qi * (H_ * DH_) + tid] =
            (part[0][tid] + part[1][tid] + part[2][tid] + part[3][tid]) * inv;
}

__global__ void cat_kernel(const __hip_bfloat16* __restrict__ n1b, const float* __restrict__ ctx,
                           __hip_bfloat16* __restrict__ catb) {
    long i = (long)blockIdx.x * blockDim.x + threadIdx.x;
    if (i >= (long)T_ * D_) return;
    int t = i >> 9, d = i & 511;
    catb[(long)t * 1024 + d]       = n1b[i];
    catb[(long)t * 1024 + 512 + d] = __float2bfloat16(ctx[i]);
}

__global__ void ne_kernel(const float* __restrict__ rec, const float* __restrict__ bemb,
                          __hip_bfloat16* __restrict__ neb, float* __restrict__ sel) {
    int n = blockIdx.x;
    __shared__ float w[NB_];
    if (threadIdx.x == 0) {
        float mx = -1e30f;
        for (int i = 0; i < NB_; i++) mx = fmaxf(mx, rec[n * NB_ + i]);
        float sm = 0.f;
        for (int i = 0; i < NB_; i++) { float e = expf(rec[n * NB_ + i] - mx); w[i] = e; sm += e; }
        float inv = 1.f / sm;
        for (int i = 0; i < NB_; i++) w[i] *= inv;
    }
    __syncthreads();
    if (threadIdx.x < NB_) sel[n * NB_ + threadIdx.x] = w[threadIdx.x];
    for (int d = threadIdx.x; d < D_; d += blockDim.x) {
        float acc = 0.f;
        #pragma unroll
        for (int nb = 0; nb < NB_; nb++) acc += w[nb] * bemb[nb * D_ + d];
        neb[(long)n * D_ + d] = __float2bfloat16(acc);
    }
}

__global__ __launch_bounds__(64) void route_kernel(const float* __restrict__ scores,
                                                   const float* __restrict__ sel,
                                                   float* __restrict__ tr) {
    int t = blockIdx.x, lane = threadIdx.x;
    float myval = scores[(long)t * N_ + lane];
    float topv[K_]; int topi[K_];
    #pragma unroll
    for (int kk = 0; kk < K_; kk++) {
        float v = myval; int idx = lane;
        #pragma unroll
        for (int off = 32; off; off >>= 1) {
            float ov = __shfl_down(v, off);
            int oi = __shfl_down(idx, off);
            if (ov > v || (ov == v && oi < idx)) { v = ov; idx = oi; }
        }
        v = __shfl(v, 0); idx = __shfl(idx, 0);
        topv[kk] = v; topi[kk] = idx;
        if (lane == idx) myval = -INFINITY;
    }
    float mx = topv[0];
    float w[K_], sum = 0.f;
    #pragma unroll
    for (int kk = 0; kk < K_; kk++) { w[kk] = expf(topv[kk] - mx); sum += w[kk]; }
    float inv = 1.f / sum;
    if (lane < NB_) {
        float acc = 0.f;
        #pragma unroll
        for (int kk = 0; kk < K_; kk++) acc += w[kk] * inv * sel[topi[kk] * NB_ + lane];
        tr[(long)t * NB_ + lane] = acc;
    }
}

__global__ __launch_bounds__(64) void h_kernel(const float* __restrict__ tr,
                                               const float* __restrict__ proj,
                                               float* __restrict__ hb) {
    int t = blockIdx.x, r = threadIdx.x;
    const float* p = proj + (long)t * (NB_ * R_);
    const float* trr = tr + (long)t * NB_;
    float acc = 0.f;
    #pragma unroll
    for (int n = 0; n < NB_; n++) acc += trr[n] * p[n * R_ + r];
    hb[(long)t * R_ + r] = acc;
}

__global__ void g_kernel(const float* __restrict__ tr, const float* __restrict__ hb,
                         __hip_bfloat16* __restrict__ g) {
    long i = (long)blockIdx.x * blockDim.x + threadIdx.x;
    if (i >= (long)T_ * NB_ * R_) return;
    int t = i >> 11; int nr = i & 2047; int n = nr >> 6, r = nr & 63;
    g[i] = __float2bfloat16(tr[t * NB_ + n] * hb[t * R_ + r]);
}

__global__ void xf_kernel(const float* __restrict__ n2, const float* __restrict__ delta,
                          const float* __restrict__ alpha, int l,
                          __hip_bfloat16* __restrict__ xfb, long n) {
    long i = (long)blockIdx.x * blockDim.x + threadIdx.x;
    if (i < n) xfb[i] = __float2bfloat16(n2[i] + alpha[l] * delta[i]);
}

__global__ void add_kernel(float* __restrict__ x, const float* __restrict__ d, long n) {
    long i = (long)blockIdx.x * blockDim.x + threadIdx.x;
    if (i < n) x[i] += d[i];
}

// ------------------------------------------------------------- launch
extern "C" void kernel_launch(void* const* d_in, const int* in_sizes, int n_in,
                              void* d_out, int out_size, void* d_ws, size_t ws_size,
                              hipStream_t stream) {
    const int*   ids    = (const int*)d_in[0];
    const float* temb   = (const float*)d_in[1];
    const float* pemb   = (const float*)d_in[2];
    const float* basisA = (const float*)d_in[3];
    const float* bemb   = (const float*)d_in[4];
    const float* recipe = (const float*)d_in[5];
    const float* Wq = (const float*)d_in[6],  *bq = (const float*)d_in[7];
    const float* Wk = (const float*)d_in[8],  *bk = (const float*)d_in[9];
    const float* Wv = (const float*)d_in[10], *bv = (const float*)d_in[11];
    const float* Ws = (const float*)d_in[12], *bs = (const float*)d_in[13];
    const float* Wup = (const float*)d_in[14], *bup = (const float*)d_in[15];
    const float* Wdn = (const float*)d_in[16], *bdn = (const float*)d_in[17];
    const float* ln1g = (const float*)d_in[18], *ln1b = (const float*)d_in[19];
    const float* ln2g = (const float*)d_in[20], *ln2b = (const float*)d_in[21];
    const float* alpha = (const float*)d_in[22];
    const float* lnfg = (const float*)d_in[23], *lnfb = (const float*)d_in[24];
    float* out = (float*)d_out;
    float* W = (float*)d_ws;

    // fp32 arena (float offsets)
    float* x    = W + 0;         // 524288
    float* buf1 = W + 524288;    // n1/n2/lnf f32
    float* qb   = W + 1048576;
    float* kb   = W + 1572864;
    float* vb   = W + 2097152;
    float* ctxb = W + 2621440;
    float* scb  = W + 3145728;   // 65536
    float* trb  = W + 3211264;   // 32768
    float* hb   = W + 3244032;   // 65536
    float* sel  = W + 3309568;   // 2048
    float* P    = W + 3311616;   // proj f32 out 2097152
    float* DB   = W + 5408768;   // delta / down out 524288
    // bf16 arena
    __hip_bfloat16* SB = (__hip_bfloat16*)(W + 5933056);
    __hip_bfloat16* tembB  = SB + 0;
    __hip_bfloat16* WqT    = SB + 16384000;
    __hip_bfloat16* WkT    = SB + 17432576;
    __hip_bfloat16* WvT    = SB + 18481152;
    __hip_bfloat16* WsT    = SB + 19529728;
    __hip_bfloat16* WupT   = SB + 21626880;
    __hip_bfloat16* WdnT   = SB + 25821184;
    __hip_bfloat16* projT  = SB + 30015488;
    __hip_bfloat16* deltaT = SB + 31064064;
    __hip_bfloat16* neB    = SB + 32112640;
    __hip_bfloat16* n1B    = SB + 32145408;
    __hip_bfloat16* catB   = SB + 32669696;
    __hip_bfloat16* qryB   = SB + 33718272;
    __hip_bfloat16* n2B    = SB + 34242560;
    __hip_bfloat16* xfB    = SB + 34766848;
    __hip_bfloat16* gB     = SB + 35291136;
    __hip_bfloat16* ffhB   = SB + 37388288;

    dim3 blk(256);
    // ---- one-time conversions ----
    cvt_temb<<<16000, blk, 0, stream>>>(temb, tembB);
    basis_prep<<<4096, blk, 0, stream>>>(basisA, projT, deltaT);
    tcvt<<<dim3(16, 16, 4), blk, 0, stream>>>(Wq, D_, (long)D_ * D_, WqT, D_, (long)D_ * D_);
    tcvt<<<dim3(16, 16, 4), blk, 0, stream>>>(Wk, D_, (long)D_ * D_, WkT, D_, (long)D_ * D_);
    tcvt<<<dim3(16, 16, 4), blk, 0, stream>>>(Wv, D_, (long)D_ * D_, WvT, D_, (long)D_ * D_);
    tcvt<<<dim3(16, 32, 4), blk, 0, stream>>>(Ws, D_, (long)2 * D_ * D_, WsT, 2 * D_, (long)2 * D_ * D_);
    tcvt<<<dim3(64, 16, 4), blk, 0, stream>>>(Wup, DFF_, (long)D_ * DFF_, WupT, D_, (long)D_ * DFF_);
    tcvt<<<dim3(16, 64, 4), blk, 0, stream>>>(Wdn, D_, (long)DFF_ * D_, WdnT, DFF_, (long)DFF_ * D_);
    embed_kernel<<<T_, blk, 0, stream>>>(ids, temb, pemb, x);

    for (int l = 0; l < L_; l++) {
        ne_kernel<<<N_, blk, 0, stream>>>(recipe + (long)l * N_ * NB_, bemb, neB, sel);
        ln_kernel<<<T_, blk, 0, stream>>>(x, ln1g + l * D_, ln1b + l * D_, buf1, n1B);
        // QKV: [1024,512] = n1B @ WqT^T   (64x64 tiles -> 128 blocks)
        gemm_mfma<64, 64, 2, 2, 0, 0><<<dim3(8, 16), blk, 0, stream>>>(
            n1B, D_, 0, WqT + (long)l * D_ * D_, D_, 0, bq + l * D_, qb, D_, 0, D_);
        gemm_mfma<64, 64, 2, 2, 0, 0><<<dim3(8, 16), blk, 0, stream>>>(
            n1B, D_, 0, WkT + (long)l * D_ * D_, D_, 0, bk + l * D_, kb, D_, 0, D_);
        gemm_mfma<64, 64, 2, 2, 0, 0><<<dim3(8, 16), blk, 0, stream>>>(
            n1B, D_, 0, WvT + (long)l * D_ * D_, D_, 0, bv + l * D_, vb, D_, 0, D_);
        attn_kernel<<<dim3(S_, H_, B_), blk, 0, stream>>>(qb, kb, vb, ctxb);
        cat_kernel<<<(T_ * D_ + 255) / 256, blk, 0, stream>>>(n1B, ctxb, catB);
        // query = cat @ Ws + bs -> bf16
        gemm_mfma<64, 64, 2, 2, 1, 0><<<dim3(8, 16), blk, 0, stream>>>(
            catB, 2 * D_, 0, WsT + (long)l * 2 * D_ * D_, 2 * D_, 0, bs + l * D_,
            qryB, D_, 0, 2 * D_);
        // scores = query @ ne^T  (f32 out)
        gemm_mfma<128, 64, 2, 2, 0, 0><<<dim3(1, 8), blk, 0, stream>>>(
            qryB, D_, 0, neB, D_, 0, nullptr, scb, N_, 0, D_);
        route_kernel<<<T_, dim3(64), 0, stream>>>(scb, sel, trb);
        ln_kernel<<<T_, blk, 0, stream>>>(x, ln2g + l * D_, ln2b + l * D_, buf1, n2B);
        // proj: batched over n (z=32): [1024,512] @ [512,64]
        gemm_mfma<128, 64, 2, 2, 0, 0><<<dim3(1, 8, NB_), blk, 0, stream>>>(
            n2B, D_, 0, projT, D_, (long)R_ * D_, nullptr, P, NB_ * R_, R_, D_);
        h_kernel<<<T_, dim3(64), 0, stream>>>(trb, P, hb);
        g_kernel<<<(T_ * NB_ * R_ + 255) / 256, blk, 0, stream>>>(trb, hb, gB);
        // delta = g @ deltaT^T : [1024,2048] @ [2048,512]
        gemm_mfma<64, 64, 2, 2, 0, 0><<<dim3(8, 16), blk, 0, stream>>>(
            gB, NB_ * R_, 0, deltaT, NB_ * R_, 0, nullptr, DB, D_, 0, NB_ * R_);
        xf_kernel<<<(T_ * D_ + 255) / 256, blk, 0, stream>>>(buf1, DB, alpha, l, xfB, (long)T_ * D_);
        // FFN up (+gelu, bf16 out): [1024,2048]
        gemm_mfma<128, 128, 2, 2, 1, 1><<<dim3(16, 8), blk, 0, stream>>>(
            xfB, D_, 0, WupT + (long)l * D_ * DFF_, D_, 0, bup + l * DFF_,
            ffhB, DFF_, 0, D_);
        // FFN down: [1024,512]
        gemm_mfma<64, 64, 2, 2, 0, 0><<<dim3(8, 16), blk, 0, stream>>>(
            ffhB, DFF_, 0, WdnT + (long)l * DFF_ * D_, DFF_, 0, bdn + l * D_,
            DB, D_, 0, DFF_);
        add_kernel<<<(T_ * D_ + 255) / 256, blk, 0, stream>>>(x, DB, (long)T_ * D_);
    }
    // final LN + tied head
    ln_kernel<<<T_, blk, 0, stream>>>(x, lnfg, lnfb, buf1, n1B);
    gemm_mfma<128, 128, 2, 2, 0, 0><<<dim3(250, 8), blk, 0, stream>>>(
        n1B, D_, 0, tembB, D_, 0, nullptr, out, V_, 0, D_);
}

// Round 3
// 839.390 us; speedup vs baseline: 11.2501x; 1.5847x over previous
//
#include <hip/hip_runtime.h>
#include <hip/hip_bf16.h>
#include <math.h>

// Problem constants
#define V_  32000
#define D_  512
#define DFF_ 2048
#define L_  4
#define H_  8
#define N_  64
#define K_  8
#define NB_ 32
#define R_  64
#define B_  2
#define S_  512
#define T_  1024   // B*S
#define DH_ 64

typedef short bhalf8 __attribute__((ext_vector_type(8)));
typedef float floatx4 __attribute__((ext_vector_type(4)));

#define GLOAD16(gp, lp) __builtin_amdgcn_global_load_lds( \
    (const __attribute__((address_space(1))) void*)(gp), \
    (__attribute__((address_space(3))) void*)(lp), 16, 0, 0)

__device__ __forceinline__ float gelu_f(float v) {
    return 0.5f * v * (1.0f + erff(v * 0.70710678118654752f));
}

__device__ __forceinline__ unsigned pk2(float a, float b) {
    unsigned ua = (unsigned)__bfloat16_as_ushort(__float2bfloat16(a));
    unsigned ub = (unsigned)__bfloat16_as_ushort(__float2bfloat16(b));
    return ua | (ub << 16);
}

// ------------------------------------------------------------- MFMA GEMM
// C[M,N] = A[M,K] @ Bt[N,K]^T (+bias). A,Bt bf16 row-major. 256 threads,
// 4 waves in WR x WC grid. BK=64, LDS XOR-swizzled (16B unit u ^= row&7).
// STORE: 0=f32, 1=bf16. ACT: 0=none, 1=gelu.
template<int BM, int BN, int WR, int WC, int STORE, int ACT>
__global__ __launch_bounds__(256) void gemm_mfma(
    const __hip_bfloat16* __restrict__ A, int lda, long sA,
    const __hip_bfloat16* __restrict__ Bt, int ldb, long sB,
    const float* __restrict__ bias,
    void* __restrict__ Cv, int ldc, long sC,
    int K)
{
    constexpr int FM = BM / WR / 16;
    constexpr int FN = BN / WC / 16;
    constexpr int ACH = BM * 8;   // 16B chunks in A tile (BM rows x 8 units)
    constexpr int BCH = BN * 8;
    __shared__ __align__(16) short As[BM * 64];
    __shared__ __align__(16) short Bs[BN * 64];
    const int tid = threadIdx.x;
    const int z = blockIdx.z;
    A  += (long)z * sA;
    Bt += (long)z * sB;
    const int bm = blockIdx.y * BM, bn = blockIdx.x * BN;
    const int w = tid >> 6, lane = tid & 63;
    const int wr = w / WC, wc = w % WC;
    const int moff = wr * (BM / WR), noff = wc * (BN / WC);
    floatx4 acc[FM][FN] = {};

    for (int k0 = 0; k0 < K; k0 += 64) {
        #pragma unroll
        for (int i = 0; i < ACH / 256; i++) {
            int c = tid + i * 256;
            int m = c >> 3, u = (c & 7) ^ (m & 7);     // pre-swizzled source
            const __hip_bfloat16* src = A + (long)(bm + m) * lda + k0 + u * 8;
            char* dst = (char*)As + (w * 64 + i * 256) * 16;  // wave-uniform base
            GLOAD16(src, dst);
        }
        #pragma unroll
        for (int i = 0; i < BCH / 256; i++) {
            int c = tid + i * 256;
            int m = c >> 3, u = (c & 7) ^ (m & 7);
            const __hip_bfloat16* src = Bt + (long)(bn + m) * ldb + k0 + u * 8;
            char* dst = (char*)Bs + (w * 64 + i * 256) * 16;
            GLOAD16(src, dst);
        }
        __syncthreads();
        #pragma unroll
        for (int kk = 0; kk < 2; kk++) {
            bhalf8 af[FM], bf[FN];
            #pragma unroll
            for (int fm = 0; fm < FM; fm++) {
                int row = moff + fm * 16 + (lane & 15);
                int u = (kk * 4 + (lane >> 4)) ^ (row & 7);
                af[fm] = *(const bhalf8*)((const char*)As + row * 128 + u * 16);
            }
            #pragma unroll
            for (int fn = 0; fn < FN; fn++) {
                int row = noff + fn * 16 + (lane & 15);
                int u = (kk * 4 + (lane >> 4)) ^ (row & 7);
                bf[fn] = *(const bhalf8*)((const char*)Bs + row * 128 + u * 16);
            }
            #pragma unroll
            for (int fm = 0; fm < FM; fm++)
                #pragma unroll
                for (int fn = 0; fn < FN; fn++)
                    acc[fm][fn] = __builtin_amdgcn_mfma_f32_16x16x32_bf16(
                        af[fm], bf[fn], acc[fm][fn], 0, 0, 0);
        }
        __syncthreads();
    }

    float* Cf = (float*)Cv;
    __hip_bfloat16* Cb = (__hip_bfloat16*)Cv;
    const long zoff = (long)z * sC;
    const int lr = lane >> 4, lc = lane & 15;
    #pragma unroll
    for (int fm = 0; fm < FM; fm++) {
        #pragma unroll
        for (int fn = 0; fn < FN; fn++) {
            int cN = bn + noff + fn * 16 + lc;
            float bv = bias ? bias[cN] : 0.f;
            #pragma unroll
            for (int i = 0; i < 4; i++) {
                int rM = bm + moff + fm * 16 + lr * 4 + i;
                float v = acc[fm][fn][i] + bv;
                if (ACT == 1) v = gelu_f(v);
                long idx = zoff + (long)rM * ldc + cN;
                if (STORE == 0) Cf[idx] = v;
                else            Cb[idx] = __float2bfloat16(v);
            }
        }
    }
}

// ------------------------------------------------------------- flash attention
// Q,K from qkv[T][1536] (q cols 0-511, k cols 512-1023); V pre-transposed
// Vt[b*8+h][dh][s] bf16. Output: bf16 ctx into catB[t][1024] second half.
// Grid (8 qtiles, H, B), 256 thr = 4 waves x 16 q-rows.
__global__ __launch_bounds__(256) void attn_mfma(
    const __hip_bfloat16* __restrict__ qkv,
    const __hip_bfloat16* __restrict__ vt,
    __hip_bfloat16* __restrict__ catB)
{
    __shared__ short pbuf[4][16][72];   // per-wave P tile, 144B row stride
    const int tid = threadIdx.x;
    const int w = tid >> 6, lane = tid & 63;
    const int g = lane >> 4, ql = lane & 15;
    const int h = blockIdx.y, b = blockIdx.z;
    const int qbase = blockIdx.x * 64 + w * 16;

    const long qrow = ((long)(b * S_ + qbase + ql)) * 1536 + h * DH_;
    bhalf8 qa0 = *(const bhalf8*)(qkv + qrow + g * 8);
    bhalf8 qa1 = *(const bhalf8*)(qkv + qrow + 32 + g * 8);
    const __hip_bfloat16* kB = qkv + 512;
    const __hip_bfloat16* vbase = vt + ((long)(b * H_ + h)) * DH_ * S_;

    floatx4 o[4] = {};   // O[q 16][dh 64] as 4 col-tiles
    float m = -INFINITY, ls = 0.f;
    const float SC = 0.125f * 1.44269504088896f;   // scale * log2(e)
    const int nblk = blockIdx.x + 1;

    for (int kvb = 0; kvb < nblk; kvb++) {
        const int kb0 = kvb * 64;
        floatx4 st[4];   // S^T tiles: [kv 16][q 16] x4 kv-subtiles
        #pragma unroll
        for (int t = 0; t < 4; t++) {
            long krow = ((long)(b * S_ + kb0 + t * 16 + ql)) * 1536 + h * DH_;
            bhalf8 ka0 = *(const bhalf8*)(kB + krow + g * 8);
            bhalf8 ka1 = *(const bhalf8*)(kB + krow + 32 + g * 8);
            floatx4 z = {};
            z = __builtin_amdgcn_mfma_f32_16x16x32_bf16(ka0, qa0, z, 0, 0, 0);
            z = __builtin_amdgcn_mfma_f32_16x16x32_bf16(ka1, qa1, z, 0, 0, 0);
            st[t] = z;
        }
        // mask + row-max (q is lane-local: col=ql)
        const int q = qbase + ql;
        float p[4][4];
        float m4 = -INFINITY;
        #pragma unroll
        for (int t = 0; t < 4; t++)
            #pragma unroll
            for (int i = 0; i < 4; i++) {
                int kv = kb0 + t * 16 + g * 4 + i;
                float v = (kv <= q) ? st[t][i] * SC : -INFINITY;
                p[t][i] = v; m4 = fmaxf(m4, v);
            }
        m4 = fmaxf(m4, __shfl_xor(m4, 16));
        m4 = fmaxf(m4, __shfl_xor(m4, 32));
        float mnew = fmaxf(m, m4);
        float corr = exp2f(m - mnew);
        m = mnew;
        float lsum = 0.f;
        #pragma unroll
        for (int t = 0; t < 4; t++)
            #pragma unroll
            for (int i = 0; i < 4; i++) {
                float e = exp2f(p[t][i] - mnew);
                p[t][i] = e; lsum += e;
            }
        lsum += __shfl_xor(lsum, 16);
        lsum += __shfl_xor(lsum, 32);
        ls = ls * corr + lsum;
        // P^T -> P[q][kv] bf16 in LDS (dword writes, clean banks)
        unsigned* prow = (unsigned*)&pbuf[w][ql][0];
        #pragma unroll
        for (int t = 0; t < 4; t++) {
            prow[t * 8 + g * 2]     = pk2(p[t][0], p[t][1]);
            prow[t * 8 + g * 2 + 1] = pk2(p[t][2], p[t][3]);
        }
        // O rescale: O rows are q-local g*4+i; stats live in lane (g*4+i)
        #pragma unroll
        for (int i = 0; i < 4; i++) {
            float c = __shfl(corr, g * 4 + i);
            #pragma unroll
            for (int dt = 0; dt < 4; dt++) o[dt][i] *= c;
        }
        __syncthreads();
        #pragma unroll
        for (int ks = 0; ks < 2; ks++) {
            bhalf8 pa = *(const bhalf8*)&pbuf[w][ql][ks * 32 + g * 8];
            #pragma unroll
            for (int dt = 0; dt < 4; dt++) {
                bhalf8 vb = *(const bhalf8*)(vbase + (long)(dt * 16 + ql) * S_ + kb0 + ks * 32 + g * 8);
                o[dt] = __builtin_amdgcn_mfma_f32_16x16x32_bf16(pa, vb, o[dt], 0, 0, 0);
            }
        }
        __syncthreads();
    }
    const float inv = 1.f / ls;
    #pragma unroll
    for (int i = 0; i < 4; i++) {
        float iv = __shfl(inv, g * 4 + i);
        int trow = b * S_ + qbase + g * 4 + i;
        #pragma unroll
        for (int dt = 0; dt < 4; dt++)
            catB[(long)trow * 1024 + 512 + h * DH_ + dt * 16 + ql] =
                __float2bfloat16(o[dt][i] * iv);
    }
}

// V [t][1536 cols, v at +1024] -> Vt[b*8+h][dh][s]
__global__ __launch_bounds__(256) void vtrans(const __hip_bfloat16* __restrict__ qkv,
                                              __hip_bfloat16* __restrict__ vt) {
    __shared__ short tl[32][33];
    int bh = blockIdx.z; int b = bh >> 3, h = bh & 7;
    int s0 = blockIdx.x * 32, d0 = blockIdx.y * 32;
    int tx = threadIdx.x & 31, ty = threadIdx.x >> 5;
    #pragma unroll
    for (int r = 0; r < 4; r++)
        tl[ty * 4 + r][tx] = *(const short*)(qkv + (long)(b * S_ + s0 + ty * 4 + r) * 1536
                                             + 1024 + h * DH_ + d0 + tx);
    __syncthreads();
    #pragma unroll
    for (int r = 0; r < 4; r++)
        *(short*)(vt + (long)bh * DH_ * S_ + (long)(d0 + ty * 4 + r) * S_ + s0 + tx)
            = tl[tx][ty * 4 + r];
}

// ------------------------------------------------------------- conversions
__global__ __launch_bounds__(256) void tcvt(const float* __restrict__ in, int ldn, long sIn,
                                            __hip_bfloat16* __restrict__ out, int ldk, long sOut) {
    __shared__ float t[32][33];
    in  += (long)blockIdx.z * sIn;
    out += (long)blockIdx.z * sOut;
    int k0 = blockIdx.y * 32, n0 = blockIdx.x * 32;
    int tx = threadIdx.x & 31, ty = threadIdx.x >> 5;
    #pragma unroll
    for (int r = 0; r < 4; r++) t[ty * 4 + r][tx] = in[(long)(k0 + ty * 4 + r) * ldn + n0 + tx];
    __syncthreads();
    #pragma unroll
    for (int r = 0; r < 4; r++)
        out[(long)(n0 + ty * 4 + r) * ldk + k0 + tx] = __float2bfloat16(t[tx][ty * 4 + r]);
}

__global__ void cvt_temb(const float* __restrict__ in, __hip_bfloat16* __restrict__ out) {
    long i = ((long)blockIdx.x * 256 + threadIdx.x) * 4;
    float4 v = *(const float4*)(in + i);
    out[i]     = __float2bfloat16(v.x);
    out[i + 1] = __float2bfloat16(v.y);
    out[i + 2] = __float2bfloat16(v.z);
    out[i + 3] = __float2bfloat16(v.w);
}

__global__ void basis_prep(const float* __restrict__ A,
                           __hip_bfloat16* __restrict__ projT,
                           __hip_bfloat16* __restrict__ deltaT) {
    long i = (long)blockIdx.x * 256 + threadIdx.x;
    if (i >= (long)NB_ * D_ * R_) return;
    int r = i & 63; int d = (i >> 6) & 511; int n = i >> 15;
    __hip_bfloat16 v = __float2bfloat16(A[i]);
    projT[((long)n * R_ + r) * D_ + d] = v;
    deltaT[(long)d * (NB_ * R_) + n * R_ + r] = v;
}

__global__ void bias_cat(const float* __restrict__ bq, const float* __restrict__ bk,
                         const float* __restrict__ bv, float* __restrict__ o) {
    int i = blockIdx.x * 256 + threadIdx.x;   // L*1536
    int l = i / 1536, j = i % 1536;
    float v = (j < 512) ? bq[l * 512 + j] : (j < 1024) ? bk[l * 512 + j - 512]
                                                       : bv[l * 512 + j - 1024];
    o[i] = v;
}

// ------------------------------------------------------------- helpers
__global__ void embed_kernel(const int* __restrict__ ids, const float* __restrict__ temb,
                             const float* __restrict__ pemb, float* __restrict__ x) {
    int t = blockIdx.x;
    int s = t % S_;
    int id = ids[t];
    for (int d = threadIdx.x; d < D_; d += blockDim.x)
        x[(long)t * D_ + d] = temb[(long)id * D_ + d] + pemb[(long)s * D_ + d];
}

__global__ __launch_bounds__(256) void ln_kernel(const float* __restrict__ in,
                                                 const float* __restrict__ g,
                                                 const float* __restrict__ b,
                                                 float* __restrict__ outf,
                                                 __hip_bfloat16* __restrict__ outb, int ldo) {
    int t = blockIdx.x;
    const float* row = in + (long)t * D_;
    int tid = threadIdx.x;
    float v0 = row[tid], v1 = row[tid + 256];
    __shared__ float red[256];
    red[tid] = v0 + v1; __syncthreads();
    for (int off = 128; off; off >>= 1) { if (tid < off) red[tid] += red[tid + off]; __syncthreads(); }
    float mean = red[0] * (1.0f / D_); __syncthreads();
    float d0 = v0 - mean, d1 = v1 - mean;
    red[tid] = d0 * d0 + d1 * d1; __syncthreads();
    for (int off = 128; off; off >>= 1) { if (tid < off) red[tid] += red[tid + off]; __syncthreads(); }
    float rstd = rsqrtf(red[0] * (1.0f / D_) + 1e-5f);
    float o0 = d0 * rstd * g[tid]       + b[tid];
    float o1 = d1 * rstd * g[tid + 256] + b[tid + 256];
    if (outf) {
        outf[(long)t * D_ + tid]       = o0;
        outf[(long)t * D_ + tid + 256] = o1;
    }
    outb[(long)t * ldo + tid]       = __float2bfloat16(o0);
    outb[(long)t * ldo + tid + 256] = __float2bfloat16(o1);
}

__global__ void ne_kernel(const float* __restrict__ rec, const float* __restrict__ bemb,
                          __hip_bfloat16* __restrict__ neb, float* __restrict__ sel) {
    int n = blockIdx.x;
    __shared__ float w[NB_];
    if (threadIdx.x == 0) {
        float mx = -1e30f;
        for (int i = 0; i < NB_; i++) mx = fmaxf(mx, rec[n * NB_ + i]);
        float sm = 0.f;
        for (int i = 0; i < NB_; i++) { float e = expf(rec[n * NB_ + i] - mx); w[i] = e; sm += e; }
        float inv = 1.f / sm;
        for (int i = 0; i < NB_; i++) w[i] *= inv;
    }
    __syncthreads();
    if (threadIdx.x < NB_) sel[n * NB_ + threadIdx.x] = w[threadIdx.x];
    for (int d = threadIdx.x; d < D_; d += blockDim.x) {
        float acc = 0.f;
        #pragma unroll
        for (int nb = 0; nb < NB_; nb++) acc += w[nb] * bemb[nb * D_ + d];
        neb[(long)n * D_ + d] = __float2bfloat16(acc);
    }
}

__global__ __launch_bounds__(64) void route_kernel(const float* __restrict__ scores,
                                                   const float* __restrict__ sel,
                                                   float* __restrict__ tr) {
    int t = blockIdx.x, lane = threadIdx.x;
    float myval = scores[(long)t * N_ + lane];
    float topv[K_]; int topi[K_];
    #pragma unroll
    for (int kk = 0; kk < K_; kk++) {
        float v = myval; int idx = lane;
        #pragma unroll
        for (int off = 32; off; off >>= 1) {
            float ov = __shfl_down(v, off);
            int oi = __shfl_down(idx, off);
            if (ov > v || (ov == v && oi < idx)) { v = ov; idx = oi; }
        }
        v = __shfl(v, 0); idx = __shfl(idx, 0);
        topv[kk] = v; topi[kk] = idx;
        if (lane == idx) myval = -INFINITY;
    }
    float mx = topv[0];
    float w[K_], sum = 0.f;
    #pragma unroll
    for (int kk = 0; kk < K_; kk++) { w[kk] = expf(topv[kk] - mx); sum += w[kk]; }
    float inv = 1.f / sum;
    if (lane < NB_) {
        float acc = 0.f;
        #pragma unroll
        for (int kk = 0; kk < K_; kk++) acc += w[kk] * inv * sel[topi[kk] * NB_ + lane];
        tr[(long)t * NB_ + lane] = acc;
    }
}

__global__ __launch_bounds__(64) void h_kernel(const float* __restrict__ tr,
                                               const float* __restrict__ proj,
                                               float* __restrict__ hb) {
    int t = blockIdx.x, r = threadIdx.x;
    const float* p = proj + (long)t * (NB_ * R_);
    const float* trr = tr + (long)t * NB_;
    float acc = 0.f;
    #pragma unroll
    for (int n = 0; n < NB_; n++) acc += trr[n] * p[n * R_ + r];
    hb[(long)t * R_ + r] = acc;
}

__global__ void g_kernel(const float* __restrict__ tr, const float* __restrict__ hb,
                         __hip_bfloat16* __restrict__ g) {
    long i = (long)blockIdx.x * blockDim.x + threadIdx.x;
    if (i >= (long)T_ * NB_ * R_) return;
    int t = i >> 11; int nr = i & 2047; int n = nr >> 6, r = nr & 63;
    g[i] = __float2bfloat16(tr[t * NB_ + n] * hb[t * R_ + r]);
}

__global__ void xf_kernel(const float* __restrict__ n2, const float* __restrict__ delta,
                          const float* __restrict__ alpha, int l,
                          __hip_bfloat16* __restrict__ xfb, long n) {
    long i = (long)blockIdx.x * blockDim.x + threadIdx.x;
    if (i < n) xfb[i] = __float2bfloat16(n2[i] + alpha[l] * delta[i]);
}

__global__ void add_kernel(float* __restrict__ x, const float* __restrict__ d, long n) {
    long i = (long)blockIdx.x * blockDim.x + threadIdx.x;
    if (i < n) x[i] += d[i];
}

// ------------------------------------------------------------- launch
extern "C" void kernel_launch(void* const* d_in, const int* in_sizes, int n_in,
                              void* d_out, int out_size, void* d_ws, size_t ws_size,
                              hipStream_t stream) {
    const int*   ids    = (const int*)d_in[0];
    const float* temb   = (const float*)d_in[1];
    const float* pemb   = (const float*)d_in[2];
    const float* basisA = (const float*)d_in[3];
    const float* bemb   = (const float*)d_in[4];
    const float* recipe = (const float*)d_in[5];
    const float* Wq = (const float*)d_in[6],  *bq = (const float*)d_in[7];
    const float* Wk = (const float*)d_in[8],  *bk = (const float*)d_in[9];
    const float* Wv = (const float*)d_in[10], *bv = (const float*)d_in[11];
    const float* Ws = (const float*)d_in[12], *bs = (const float*)d_in[13];
    const float* Wup = (const float*)d_in[14], *bup = (const float*)d_in[15];
    const float* Wdn = (const float*)d_in[16], *bdn = (const float*)d_in[17];
    const float* ln1g = (const float*)d_in[18], *ln1b = (const float*)d_in[19];
    const float* ln2g = (const float*)d_in[20], *ln2b = (const float*)d_in[21];
    const float* alpha = (const float*)d_in[22];
    const float* lnfg = (const float*)d_in[23], *lnfb = (const float*)d_in[24];
    float* out = (float*)d_out;
    float* W = (float*)d_ws;

    // fp32 arena (float offsets)
    float* x    = W + 0;          // 524288
    float* buf1 = W + 524288;     // n2 f32 (xf input)
    float* scb  = W + 1048576;    // 65536
    float* trb  = W + 1114112;    // 32768
    float* hb   = W + 1146880;    // 65536
    float* sel  = W + 1212416;    // 2048
    float* P    = W + 1214464;    // proj f32 2097152
    float* DB   = W + 3311616;    // delta / down out 524288
    float* bqkv = W + 3835904;    // 6144
    // bf16 arena (shorts), 16B-aligned
    __hip_bfloat16* SB = (__hip_bfloat16*)(W + 3844096);
    __hip_bfloat16* tembB  = SB + 0;          // 16384000
    __hip_bfloat16* qkvT   = SB + 16384000;   // L*1536*512 = 3145728
    __hip_bfloat16* WsT    = SB + 19529728;   // 2097152
    __hip_bfloat16* WupT   = SB + 21626880;   // 4194304
    __hip_bfloat16* WdnT   = SB + 25821184;   // 4194304
    __hip_bfloat16* projT  = SB + 30015488;   // 1048576
    __hip_bfloat16* deltaT = SB + 31064064;   // 1048576
    __hip_bfloat16* neB    = SB + 32112640;   // 32768
    __hip_bfloat16* catB   = SB + 32145408;   // T*1024 = 1048576
    __hip_bfloat16* qryB   = SB + 33193984;   // 524288
    __hip_bfloat16* n2B    = SB + 33718272;   // 524288 (also final LN out)
    __hip_bfloat16* xfB    = SB + 34242560;   // 524288
    __hip_bfloat16* gB     = SB + 34766848;   // 2097152
    __hip_bfloat16* ffhB   = SB + 36864000;   // 2097152
    __hip_bfloat16* qkvB   = SB + 38961152;   // T*1536 = 1572864
    __hip_bfloat16* VtB    = SB + 40534016;   // 16*64*512 = 524288

    dim3 blk(256);
    // ---- one-time conversions ----
    cvt_temb<<<16000, blk, 0, stream>>>(temb, tembB);
    basis_prep<<<4096, blk, 0, stream>>>(basisA, projT, deltaT);
    bias_cat<<<24, blk, 0, stream>>>(bq, bk, bv, bqkv);
    tcvt<<<dim3(16, 16, 4), blk, 0, stream>>>(Wq, D_, (long)D_ * D_, qkvT, D_, (long)1536 * D_);
    tcvt<<<dim3(16, 16, 4), blk, 0, stream>>>(Wk, D_, (long)D_ * D_, qkvT + 512 * 512, D_, (long)1536 * D_);
    tcvt<<<dim3(16, 16, 4), blk, 0, stream>>>(Wv, D_, (long)D_ * D_, qkvT + 1024 * 512, D_, (long)1536 * D_);
    tcvt<<<dim3(16, 32, 4), blk, 0, stream>>>(Ws, D_, (long)2 * D_ * D_, WsT, 2 * D_, (long)2 * D_ * D_);
    tcvt<<<dim3(64, 16, 4), blk, 0, stream>>>(Wup, DFF_, (long)D_ * DFF_, WupT, D_, (long)D_ * DFF_);
    tcvt<<<dim3(16, 64, 4), blk, 0, stream>>>(Wdn, D_, (long)DFF_ * D_, WdnT, DFF_, (long)DFF_ * D_);
    embed_kernel<<<T_, blk, 0, stream>>>(ids, temb, pemb, x);

    for (int l = 0; l < L_; l++) {
        ne_kernel<<<N_, blk, 0, stream>>>(recipe + (long)l * N_ * NB_, bemb, neB, sel);
        // n1 -> catB first half (bf16, ld 1024)
        ln_kernel<<<T_, blk, 0, stream>>>(x, ln1g + l * D_, ln1b + l * D_, nullptr, catB, 1024);
        // fused QKV: [1024,1536] bf16
        gemm_mfma<64, 64, 2, 2, 1, 0><<<dim3(24, 16), blk, 0, stream>>>(
            catB, 1024, 0, qkvT + (long)l * 1536 * 512, D_, 0, bqkv + l * 1536,
            qkvB, 1536, 0, D_);
        vtrans<<<dim3(16, 2, 16), blk, 0, stream>>>(qkvB, VtB);
        attn_mfma<<<dim3(8, H_, B_), blk, 0, stream>>>(qkvB, VtB, catB);
        // query = cat @ Ws + bs -> bf16
        gemm_mfma<64, 64, 2, 2, 1, 0><<<dim3(8, 16), blk, 0, stream>>>(
            catB, 2 * D_, 0, WsT + (long)l * 2 * D_ * D_, 2 * D_, 0, bs + l * D_,
            qryB, D_, 0, 2 * D_);
        // scores = query @ ne^T (f32 out)
        gemm_mfma<128, 64, 2, 2, 0, 0><<<dim3(1, 8), blk, 0, stream>>>(
            qryB, D_, 0, neB, D_, 0, nullptr, scb, N_, 0, D_);
        route_kernel<<<T_, dim3(64), 0, stream>>>(scb, sel, trb);
        ln_kernel<<<T_, blk, 0, stream>>>(x, ln2g + l * D_, ln2b + l * D_, buf1, n2B, 512);
        // proj: batched over n (z=32)
        gemm_mfma<128, 64, 2, 2, 0, 0><<<dim3(1, 8, NB_), blk, 0, stream>>>(
            n2B, D_, 0, projT, D_, (long)R_ * D_, nullptr, P, NB_ * R_, R_, D_);
        h_kernel<<<T_, dim3(64), 0, stream>>>(trb, P, hb);
        g_kernel<<<(T_ * NB_ * R_ + 255) / 256, blk, 0, stream>>>(trb, hb, gB);
        // delta = g @ deltaT^T
        gemm_mfma<64, 64, 2, 2, 0, 0><<<dim3(8, 16), blk, 0, stream>>>(
            gB, NB_ * R_, 0, deltaT, NB_ * R_, 0, nullptr, DB, D_, 0, NB_ * R_);
        xf_kernel<<<(T_ * D_ + 255) / 256, blk, 0, stream>>>(buf1, DB, alpha, l, xfB, (long)T_ * D_);
        // FFN up (+gelu, bf16 out)
        gemm_mfma<128, 128, 2, 2, 1, 1><<<dim3(16, 8), blk, 0, stream>>>(
            xfB, D_, 0, WupT + (long)l * D_ * DFF_, D_, 0, bup + l * DFF_,
            ffhB, DFF_, 0, D_);
        // FFN down
        gemm_mfma<64, 64, 2, 2, 0, 0><<<dim3(8, 16), blk, 0, stream>>>(
            ffhB, DFF_, 0, WdnT + (long)l * DFF_ * D_, DFF_, 0, bdn + l * D_,
            DB, D_, 0, DFF_);
        add_kernel<<<(T_ * D_ + 255) / 256, blk, 0, stream>>>(x, DB, (long)T_ * D_);
    }
    // final LN + tied head
    ln_kernel<<<T_, blk, 0, stream>>>(x, lnfg, lnfb, nullptr, n2B, 512);
    gemm_mfma<128, 128, 2, 2, 0, 0><<<dim3(250, 8), blk, 0, stream>>>(
        n2B, D_, 0, tembB, D_, 0, nullptr, out, V_, 0, D_);
}